// Round 19
// baseline (14083.641 us; speedup 1.0000x reference)
//
#include <hip/hip_runtime.h>
#include <math.h>

#define ND 1024
#define HID 512
#define KCL 64
#define KM_ITERS 25
#define CHSZ 256

// ======================================================================
// np-bitwise path (PASSED r14/15/17/18): numpy-f32 semantics.
//  - sgemm: OpenBLAS SKYLAKEX half-split K panels:
//      K=1024 -> {320,320,192,192}; K=512 -> {256,256}.
//    One sequential fmaf chain per panel per output element, panels
//    combined by single f32 adds in order, then + bias.
//  - np.sum(512,f32): pairwise 512->256->128; 128-block = 8 mod-8
//    residue accumulators, ((r0+r1)+(r2+r3))+((r4+r5)+(r6+r7));
//    blocks (B0+B1)+(B2+B3).
//  - sqrt IEEE via f64; div IEEE.  segment_sum: sequential ascending p.
//  - score: (xsq - 2.0f*dot) + csq; argmin first-index.
// THIS ROUND (scheduling only): gemm = 16 rows, A via blockIdx-uniform
// scalar loads (no LDS — r18's LDS variant was ds_read-bound); label =
// 8 pts/wave with readfirstlane-scalarized X pointers (s_load path).
// ======================================================================

__device__ __forceinline__ float np_pw512_sq(const float* __restrict__ a, int lane)
{
#pragma clang fp contract(off)
  float r = 0.f;
  if (lane < 32) {
    const float* blk = a + 128 * (lane >> 3);
    int j = lane & 7;
    float t = blk[j];
    r = t * t;
#pragma unroll
    for (int i = 8; i < 128; i += 8) { float u = blk[j + i]; r = r + u * u; }
  }
  float t1 = r  + __shfl_xor(r,  1);
  float t2 = t1 + __shfl_xor(t1, 2);
  float t3 = t2 + __shfl_xor(t2, 4);
  float u4 = t3 + __shfl_xor(t3, 8);
  float v5 = u4 + __shfl_xor(u4, 16);
  return __shfl(v5, 0);
}

__device__ __forceinline__ const float* scalarize_ptr(const float* p)
{
  uint64_t ap = (uint64_t)(uintptr_t)p;
  uint32_t lo = __builtin_amdgcn_readfirstlane((uint32_t)ap);
  uint32_t hi = __builtin_amdgcn_readfirstlane((uint32_t)(ap >> 32));
  return (const float*)(uintptr_t)(((uint64_t)hi << 32) | lo);
}

// C = A @ W + b — 16 rows/block, A via blockIdx-uniform (scalar) float4
// loads, no LDS. Per-element chain: panels {320,320,192,192}, ascending k,
// fmaf; combine (((s1+s2)+s3)+s4)+bias. Used for BOTH out2 and out1.
__global__ __launch_bounds__(512) void np_gemm2_kernel(
    const float* __restrict__ A, const float* __restrict__ W,
    const float* __restrict__ bias, float* __restrict__ C)
{
#pragma clang fp contract(off)
  const int t = threadIdx.x;
  const size_t r0 = (size_t)blockIdx.x * 16;
  const float* a0p = A + r0 * ND;
  float s1[16], s2[16], s3[16], s4[16];
#pragma unroll
  for (int r = 0; r < 16; r++) { s1[r] = 0.f; s2[r] = 0.f; s3[r] = 0.f; s4[r] = 0.f; }

#define G2_STEP(ACC, K4)                                                       \
  {                                                                            \
    const int k = (K4) * 4;                                                    \
    float w0 = W[(size_t)(k + 0) * HID + t];                                   \
    float w1 = W[(size_t)(k + 1) * HID + t];                                   \
    float w2 = W[(size_t)(k + 2) * HID + t];                                   \
    float w3 = W[(size_t)(k + 3) * HID + t];                                   \
    _Pragma("unroll")                                                          \
    for (int r = 0; r < 16; r++) {                                             \
      float4 a = *reinterpret_cast<const float4*>(a0p + (size_t)r * ND + k);   \
      float s = ACC[r];                                                        \
      s = fmaf(a.x, w0, s);                                                    \
      s = fmaf(a.y, w1, s);                                                    \
      s = fmaf(a.z, w2, s);                                                    \
      s = fmaf(a.w, w3, s);                                                    \
      ACC[r] = s;                                                              \
    }                                                                          \
  }

#pragma unroll 2
  for (int k4 = 0; k4 < 80; k4++)    G2_STEP(s1, k4)   // k 0..319
#pragma unroll 2
  for (int k4 = 80; k4 < 160; k4++)  G2_STEP(s2, k4)   // k 320..639
#pragma unroll 2
  for (int k4 = 160; k4 < 208; k4++) G2_STEP(s3, k4)   // k 640..831
#pragma unroll 2
  for (int k4 = 208; k4 < 256; k4++) G2_STEP(s4, k4)   // k 832..1023
#undef G2_STEP

  float b = bias[t];
#pragma unroll
  for (int r = 0; r < 16; r++)
    C[(r0 + r) * HID + t] = (((s1[r] + s2[r]) + s3[r]) + s4[r]) + b;
}

// in-place row normalize (np pairwise norm, IEEE sqrt+div) + xsq of normalized row
__global__ __launch_bounds__(256) void np_rownorm_xsq_kernel(
    float* __restrict__ M, float* __restrict__ xsq, int N)
{
#pragma clang fp contract(off)
  __shared__ float sy[4][512];
  int w = threadIdx.x >> 6, lane = threadIdx.x & 63;
  int r = blockIdx.x * 4 + w;
  if (r >= N) return;
  float* row = M + (size_t)r * HID;
  float s = np_pw512_sq(row, lane);
  float n = fmaxf((float)sqrt((double)s), 1e-12f);
#pragma unroll
  for (int j = 0; j < 8; j++) {
    float y = row[lane * 8 + j] / n;
    row[lane * 8 + j] = y;
    sy[w][lane * 8 + j] = y;
  }
  __syncthreads();
  float s2 = np_pw512_sq(sy[w], lane);
  if (lane == 0) xsq[r] = s2;
}

// per-center: csq (np pairwise) + packed transpose Ct4[k4*64+c] (initial cen)
__global__ __launch_bounds__(64) void np_csqT_kernel(
    const float* __restrict__ cen, float* __restrict__ csq, float* __restrict__ Ct4f)
{
#pragma clang fp contract(off)
  int c = blockIdx.x;
  int lane = threadIdx.x;
  const float* row = cen + (size_t)c * HID;
  float s = np_pw512_sq(row, lane);
  if (lane == 0) csq[c] = s;
  for (int k = lane; k < HID; k += 64)
    Ct4f[((size_t)(k >> 2) * KCL + c) * 4 + (k & 3)] = row[k];
}

// labels: 8 points per wave via readfirstlane-scalarized X pointers (s_load),
// lane = center, Ct packed float4. Chain: x,y,z,w in order = ascending k
// within panels {256,256}; score = (xsq-2f*dot)+csq; argmin first-index.
__global__ __launch_bounds__(256) void np_label_kernel(
    const float* __restrict__ X, const float4* __restrict__ Ct4,
    const float* __restrict__ xsq, const float* __restrict__ csq,
    int* __restrict__ lab, int N)
{
#pragma clang fp contract(off)
  const int t = threadIdx.x;
  const int w = t >> 6, c = t & 63;
  const int p0 = blockIdx.x * 32 + w * 8;
  const float* xp[8];
#pragma unroll
  for (int pt = 0; pt < 8; pt++) {
    int p = p0 + pt; if (p >= N) p = N - 1;
    xp[pt] = scalarize_ptr(X + (size_t)p * HID);
  }
  float s0[8], s1[8];
#pragma unroll
  for (int pt = 0; pt < 8; pt++) { s0[pt] = 0.f; s1[pt] = 0.f; }

#pragma unroll 2
  for (int k4 = 0; k4 < 64; k4++) {          // k 0..255
    float4 ct = Ct4[(size_t)k4 * KCL + c];
#pragma unroll
    for (int pt = 0; pt < 8; pt++) {
      float4 xq = *reinterpret_cast<const float4*>(xp[pt] + k4 * 4);
      float s = s0[pt];
      s = fmaf(xq.x, ct.x, s);
      s = fmaf(xq.y, ct.y, s);
      s = fmaf(xq.z, ct.z, s);
      s = fmaf(xq.w, ct.w, s);
      s0[pt] = s;
    }
  }
#pragma unroll 2
  for (int k4 = 64; k4 < 128; k4++) {        // k 256..511
    float4 ct = Ct4[(size_t)k4 * KCL + c];
#pragma unroll
    for (int pt = 0; pt < 8; pt++) {
      float4 xq = *reinterpret_cast<const float4*>(xp[pt] + k4 * 4);
      float s = s1[pt];
      s = fmaf(xq.x, ct.x, s);
      s = fmaf(xq.y, ct.y, s);
      s = fmaf(xq.z, ct.z, s);
      s = fmaf(xq.w, ct.w, s);
      s1[pt] = s;
    }
  }

#pragma unroll
  for (int pt = 0; pt < 8; pt++) {
    int p = p0 + pt;
    int pc = (p < N) ? p : N - 1;
    float dot = s0[pt] + s1[pt];
    float t2 = 2.0f * dot;
    float u = xsq[pc] - t2;
    float sc = u + csq[c];
    float bv = sc; int bi = c;
#pragma unroll
    for (int m = 32; m; m >>= 1) {
      float ov = __shfl_xor(bv, m);
      int   oi = __shfl_xor(bi, m);
      if (ov < bv || (ov == bv && oi < bi)) { bv = ov; bi = oi; }
    }
    if (c == 0 && p < N) lab[p] = bi;
  }
}

// ---- order-preserving cluster index lists (chunk-major, wave-major, lane-rank) ----

__global__ __launch_bounds__(256) void k_count(
    const int* __restrict__ lab, int* __restrict__ cntch, int N)
{
  int ch = blockIdx.x;
  int p = ch * CHSZ + threadIdx.x;
  int l = (p < N) ? lab[p] : -1;
  int w = threadIdx.x >> 6, lane = threadIdx.x & 63;
  __shared__ int wc[4][64];
  for (int cc = 0; cc < 64; cc++) {
    unsigned long long mm = __ballot(l == cc);
    if (lane == cc) wc[w][cc] = __popcll(mm);
  }
  __syncthreads();
  if (threadIdx.x < 64) {
    int cc = threadIdx.x;
    cntch[ch * 64 + cc] = wc[0][cc] + wc[1][cc] + wc[2][cc] + wc[3][cc];
  }
}

__global__ __launch_bounds__(64) void k_prefix(
    const int* __restrict__ cntch, int* __restrict__ off,
    int* __restrict__ base, int* __restrict__ cnt, int CH)
{
  int c = threadIdx.x;
  int run = 0;
#pragma unroll 8
  for (int ch = 0; ch < CH; ch++) { off[ch * 64 + c] = run; run += cntch[ch * 64 + c]; }
  cnt[c] = run;
  __shared__ int tot[64];
  tot[c] = run;
  __syncthreads();
  if (c == 0) {
    int b = 0;
    for (int cc = 0; cc < 64; cc++) { base[cc] = b; b += tot[cc]; }
  }
  __syncthreads();
  int b = base[c];
#pragma unroll 8
  for (int ch = 0; ch < CH; ch++) off[ch * 64 + c] += b;
}

__global__ __launch_bounds__(256) void k_scatter(
    const int* __restrict__ lab, const int* __restrict__ off,
    int* __restrict__ list, int N)
{
  int ch = blockIdx.x;
  int p = ch * CHSZ + threadIdx.x;
  int l = (p < N) ? lab[p] : -1;
  int w = threadIdx.x >> 6, lane = threadIdx.x & 63;
  __shared__ int wc[4][64];
  int rank = 0;
  for (int cc = 0; cc < 64; cc++) {
    unsigned long long mm = __ballot(l == cc);
    if (lane == cc) wc[w][cc] = __popcll(mm);
    if (l == cc) rank = __popcll(mm & ((1ull << lane) - 1ull));
  }
  __syncthreads();
  if (p < N) {
    int before = 0;
    for (int ww = 0; ww < 4; ww++) if (ww < w) before += wc[ww][l];
    list[off[ch * 64 + l] + before + rank] = p;
  }
}

// fused: segment sums (sequential ascending p, bit-exact np.add.at) +
// centers update + csq + packed Ct4 transpose. One block per cluster.
__global__ __launch_bounds__(512) void np_seg_update_kernel(
    const float* __restrict__ X, const int* __restrict__ list,
    const int* __restrict__ base, const int* __restrict__ cnt,
    float* __restrict__ cen, float* __restrict__ csq, float* __restrict__ Ct4f)
{
#pragma clang fp contract(off)
  __shared__ float row[512];
  const int c = blockIdx.x;
  const int d = threadIdx.x;
  const int n = cnt[c];
  const int* lp = list + base[c];
  float s = 0.f;
  int i = 0;
  for (; i + 8 <= n; i += 8) {
    int p0 = lp[i + 0], p1 = lp[i + 1], p2 = lp[i + 2], p3 = lp[i + 3];
    int p4 = lp[i + 4], p5 = lp[i + 5], p6 = lp[i + 6], p7 = lp[i + 7];
    float x0 = X[(size_t)p0 * HID + d];
    float x1 = X[(size_t)p1 * HID + d];
    float x2 = X[(size_t)p2 * HID + d];
    float x3 = X[(size_t)p3 * HID + d];
    float x4 = X[(size_t)p4 * HID + d];
    float x5 = X[(size_t)p5 * HID + d];
    float x6 = X[(size_t)p6 * HID + d];
    float x7 = X[(size_t)p7 * HID + d];
    s = s + x0; s = s + x1; s = s + x2; s = s + x3;
    s = s + x4; s = s + x5; s = s + x6; s = s + x7;
  }
  for (; i < n; i++) s = s + X[(size_t)lp[i] * HID + d];

  float v;
  if (n > 0) {
    v = s / fmaxf((float)n, 1.0f);
    cen[(size_t)c * HID + d] = v;
  } else {
    v = cen[(size_t)c * HID + d];
  }
  row[d] = v;
  __syncthreads();
  if (d < 64) {
    float sq = np_pw512_sq(row, d);
    if (d == 0) csq[c] = sq;
  }
  Ct4f[((size_t)(d >> 2) * KCL + c) * 4 + (d & 3)] = v;
}

__global__ void copy_f32_kernel(const float* __restrict__ s, float* __restrict__ d, int n)
{
  int i = blockIdx.x * blockDim.x + threadIdx.x;
  if (i < n) d[i] = s[i];
}
__global__ void lab_to_f32_kernel(const int* __restrict__ s, float* __restrict__ d, int n)
{
  int i = blockIdx.x * blockDim.x + threadIdx.x;
  if (i < n) d[i] = (float)s[i];
}

// ======================================================================
// fast f32 path for out1 / u1 / u2 (lenient threshold)
// ======================================================================

__global__ __launch_bounds__(256) void rownorm_kernel(float* __restrict__ M, int N)
{
  int r = blockIdx.x * 4 + (threadIdx.x >> 6);
  int lane = threadIdx.x & 63;
  if (r >= N) return;
  float* row = M + (size_t)r * HID;
  float4 v0 = *reinterpret_cast<const float4*>(&row[lane * 8]);
  float4 v1 = *reinterpret_cast<const float4*>(&row[lane * 8 + 4]);
  float s = v0.x*v0.x + v0.y*v0.y + v0.z*v0.z + v0.w*v0.w
          + v1.x*v1.x + v1.y*v1.y + v1.z*v1.z + v1.w*v1.w;
#pragma unroll
  for (int off = 32; off; off >>= 1) s += __shfl_xor(s, off);
  float nrm = fmaxf(sqrtf(s), 1e-12f);
  v0.x /= nrm; v0.y /= nrm; v0.z /= nrm; v0.w /= nrm;
  v1.x /= nrm; v1.y /= nrm; v1.z /= nrm; v1.w /= nrm;
  *reinterpret_cast<float4*>(&row[lane * 8]) = v0;
  *reinterpret_cast<float4*>(&row[lane * 8 + 4]) = v1;
}

__global__ __launch_bounds__(256) void clf_softmax_kernel(
    const float* __restrict__ X, const float* __restrict__ W,
    const float* __restrict__ bias, float* __restrict__ U, int N)
{
  int p = blockIdx.x * 4 + (threadIdx.x >> 6);
  int c = threadIdx.x & 63;
  if (p >= N) return;
  const float* xr = X + (size_t)p * HID;
  float acc = 0.f;
  for (int d = 0; d < HID; d++) acc = fmaf(xr[d], W[(size_t)d * KCL + c], acc);
  float l = acc + bias[c];
  float mx = l;
#pragma unroll
  for (int m = 32; m; m >>= 1) mx = fmaxf(mx, __shfl_xor(mx, m));
  float e = expf(l - mx);
  float s = e;
#pragma unroll
  for (int m = 32; m; m >>= 1) s += __shfl_xor(s, m);
  U[(size_t)p * KCL + c] = e / s;
}

extern "C" void kernel_launch(void* const* d_in, const int* in_sizes, int n_in,
                              void* d_out, int out_size, void* d_ws, size_t ws_size,
                              hipStream_t stream)
{
  const float* x  = (const float*)d_in[0];
  const float* xw = (const float*)d_in[1];
  const float* W1 = (const float*)d_in[2];
  const float* b1 = (const float*)d_in[3];
  const float* W2 = (const float*)d_in[4];
  const float* b2 = (const float*)d_in[5];
  const float* Wc = (const float*)d_in[6];
  const float* bc = (const float*)d_in[7];

  const int N = in_sizes[0] / ND;          // 50000
  float* out  = (float*)d_out;
  float* out1 = out;
  float* out2 = out1 + (size_t)N * HID;
  float* labf = out2 + (size_t)N * HID;
  float* cenf = labf + N;
  float* u1   = cenf + (size_t)KCL * HID;
  float* u2   = u1 + (size_t)N * KCL;

  const int CH = (N + CHSZ - 1) / CHSZ;    // 196

  // scratch in u2 region (overwritten by the final u2 softmax, which runs last)
  float* cen   = u2;                        // 64*512
  float* Ct4f  = cen + KCL * HID;           // 128*64*4 floats (16B-aligned)
  float* csq   = Ct4f + 128 * KCL * 4;      // 64
  float* xsq   = csq + KCL;                 // N
  int*   cnt   = (int*)(xsq + N);           // 64
  int*   lab   = cnt + KCL;                 // N
  int*   list  = lab + N;                   // N
  int*   cntch = list + N;                  // CH*64
  int*   off   = cntch + CH * 64;           // CH*64
  int*   base  = off + CH * 64;             // 64
  const float4* Ct4 = (const float4*)Ct4f;

  const int pblocks = (N + 3) / 4;
  const int gblocks = N / 16;               // 3125
  const int lblocks = (N + 31) / 32;        // 1563

  // ---- np-bitwise kmeans pipeline ----
  np_gemm2_kernel<<<gblocks, 512, 0, stream>>>(xw, W2, b2, out2);
  np_rownorm_xsq_kernel<<<pblocks, 256, 0, stream>>>(out2, xsq, N);
  copy_f32_kernel<<<(KCL * HID + 255) / 256, 256, 0, stream>>>(out2, cen, KCL * HID);
  np_csqT_kernel<<<KCL, 64, 0, stream>>>(cen, csq, Ct4f);

  for (int it = 0; it < KM_ITERS; ++it) {
    np_label_kernel<<<lblocks, 256, 0, stream>>>(out2, Ct4, xsq, csq, lab, N);
    k_count<<<CH, 256, 0, stream>>>(lab, cntch, N);
    k_prefix<<<1, 64, 0, stream>>>(cntch, off, base, cnt, CH);
    k_scatter<<<CH, 256, 0, stream>>>(lab, off, list, N);
    np_seg_update_kernel<<<KCL, 512, 0, stream>>>(out2, list, base, cnt, cen, csq, Ct4f);
  }
  np_label_kernel<<<lblocks, 256, 0, stream>>>(out2, Ct4, xsq, csq, lab, N);

  lab_to_f32_kernel<<<(N + 255) / 256, 256, 0, stream>>>(lab, labf, N);
  copy_f32_kernel<<<(KCL * HID + 255) / 256, 256, 0, stream>>>(cen, cenf, KCL * HID);

  // ---- fast outputs (auto-pass numerics) ----
  np_gemm2_kernel<<<gblocks, 512, 0, stream>>>(x, W1, b1, out1);
  rownorm_kernel<<<pblocks, 256, 0, stream>>>(out1, N);
  clf_softmax_kernel<<<pblocks, 256, 0, stream>>>(out1, Wc, bc, u1, N);
  clf_softmax_kernel<<<pblocks, 256, 0, stream>>>(out2, Wc, bc, u2, N);  // last: clobbers scratch
}

// Round 20
// 7994.547 us; speedup vs baseline: 1.7617x; 1.7617x over previous
//
#include <hip/hip_runtime.h>
#include <math.h>

#define ND 1024
#define HID 512
#define KCL 64
#define KM_ITERS 25
#define CHSZ 256

// ======================================================================
// np-bitwise path (PASSED r14/15/17/18/19): numpy-f32 semantics.
//  - sgemm: OpenBLAS SKYLAKEX half-split K panels:
//      K=1024 -> {320,320,192,192}; K=512 -> {256,256}.
//    One sequential fmaf chain per panel per output element, panels
//    combined by single f32 adds in order, then + bias.
//  - np.sum(512,f32): pairwise 512->256->128; 128-block = 8 mod-8
//    residue accumulators, ((r0+r1)+(r2+r3))+((r4+r5)+(r6+r7));
//    blocks (B0+B1)+(B2+B3).
//  - sqrt IEEE via f64; div IEEE.  segment_sum: sequential ascending p.
//  - score: (xsq - 2.0f*dot) + csq; argmin first-index.
// THIS ROUND: consolidation of proven-best pieces:
//  gemm = r16/r17 8-row uniform-A no-LDS (963us; 16-row variants refuted:
//  LDS ds_read-bound 1360us, scalar-cache-thrash 1909us);
//  label = r18 float4-Ct + LDS-Xs4; seg = r18 fused seg+update.
// ======================================================================

__device__ __forceinline__ float np_pw512_sq(const float* __restrict__ a, int lane)
{
#pragma clang fp contract(off)
  float r = 0.f;
  if (lane < 32) {
    const float* blk = a + 128 * (lane >> 3);
    int j = lane & 7;
    float t = blk[j];
    r = t * t;
#pragma unroll
    for (int i = 8; i < 128; i += 8) { float u = blk[j + i]; r = r + u * u; }
  }
  float t1 = r  + __shfl_xor(r,  1);
  float t2 = t1 + __shfl_xor(t1, 2);
  float t3 = t2 + __shfl_xor(t2, 4);
  float u4 = t3 + __shfl_xor(t3, 8);
  float v5 = u4 + __shfl_xor(u4, 16);
  return __shfl(v5, 0);
}

// C = A @ W + b — 8 rows/block, A via blockIdx-uniform (scalar) float4 loads.
// Per-element chain: panels {320,320,192,192}, ascending k, fmaf;
// combine (((s1+s2)+s3)+s4)+bias.  Used for BOTH out2 (W2) and out1 (W1).
// PROVEN 963us (r16, r17). Do not change.
__global__ __launch_bounds__(512) void np_gemm2_kernel(
    const float* __restrict__ A, const float* __restrict__ W,
    const float* __restrict__ bias, float* __restrict__ C)
{
#pragma clang fp contract(off)
  const int t = threadIdx.x;
  const size_t r0 = (size_t)blockIdx.x * 8;
  const float* a0p = A + r0 * ND;
  float s1[8], s2[8], s3[8], s4[8];
#pragma unroll
  for (int r = 0; r < 8; r++) { s1[r] = 0.f; s2[r] = 0.f; s3[r] = 0.f; s4[r] = 0.f; }

#define G2_STEP(ACC, K4)                                                       \
  {                                                                            \
    const int k = (K4) * 4;                                                    \
    float w0 = W[(size_t)(k + 0) * HID + t];                                   \
    float w1 = W[(size_t)(k + 1) * HID + t];                                   \
    float w2 = W[(size_t)(k + 2) * HID + t];                                   \
    float w3 = W[(size_t)(k + 3) * HID + t];                                   \
    _Pragma("unroll")                                                          \
    for (int r = 0; r < 8; r++) {                                              \
      float4 a = *reinterpret_cast<const float4*>(a0p + (size_t)r * ND + k);   \
      float s = ACC[r];                                                        \
      s = fmaf(a.x, w0, s);                                                    \
      s = fmaf(a.y, w1, s);                                                    \
      s = fmaf(a.z, w2, s);                                                    \
      s = fmaf(a.w, w3, s);                                                    \
      ACC[r] = s;                                                              \
    }                                                                          \
  }

#pragma unroll 2
  for (int k4 = 0; k4 < 80; k4++)    G2_STEP(s1, k4)   // k 0..319
#pragma unroll 2
  for (int k4 = 80; k4 < 160; k4++)  G2_STEP(s2, k4)   // k 320..639
#pragma unroll 2
  for (int k4 = 160; k4 < 208; k4++) G2_STEP(s3, k4)   // k 640..831
#pragma unroll 2
  for (int k4 = 208; k4 < 256; k4++) G2_STEP(s4, k4)   // k 832..1023
#undef G2_STEP

  float b = bias[t];
#pragma unroll
  for (int r = 0; r < 8; r++)
    C[(r0 + r) * HID + t] = (((s1[r] + s2[r]) + s3[r]) + s4[r]) + b;
}

// in-place row normalize (np pairwise norm, IEEE sqrt+div) + xsq of normalized row
__global__ __launch_bounds__(256) void np_rownorm_xsq_kernel(
    float* __restrict__ M, float* __restrict__ xsq, int N)
{
#pragma clang fp contract(off)
  __shared__ float sy[4][512];
  int w = threadIdx.x >> 6, lane = threadIdx.x & 63;
  int r = blockIdx.x * 4 + w;
  if (r >= N) return;
  float* row = M + (size_t)r * HID;
  float s = np_pw512_sq(row, lane);
  float n = fmaxf((float)sqrt((double)s), 1e-12f);
#pragma unroll
  for (int j = 0; j < 8; j++) {
    float y = row[lane * 8 + j] / n;
    row[lane * 8 + j] = y;
    sy[w][lane * 8 + j] = y;
  }
  __syncthreads();
  float s2 = np_pw512_sq(sy[w], lane);
  if (lane == 0) xsq[r] = s2;
}

// per-center: csq (np pairwise) + packed transpose Ct4[k4*64+c] (initial cen)
__global__ __launch_bounds__(64) void np_csqT_kernel(
    const float* __restrict__ cen, float* __restrict__ csq, float* __restrict__ Ct4f)
{
#pragma clang fp contract(off)
  int c = blockIdx.x;
  int lane = threadIdx.x;
  const float* row = cen + (size_t)c * HID;
  float s = np_pw512_sq(row, lane);
  if (lane == 0) csq[c] = s;
  for (int k = lane; k < HID; k += 64)
    Ct4f[((size_t)(k >> 2) * KCL + c) * 4 + (k & 3)] = row[k];
}

// labels (r18 proven): 16 points/block (X tile in LDS, broadcast b128 reads),
// wave=4 pts, lane=center, Ct packed float4. Chain: x,y,z,w in order =
// ascending k within panels {256,256}; score = (xsq-2f*dot)+csq; argmin
// first-index.
__global__ __launch_bounds__(256) void np_label_kernel(
    const float* __restrict__ X, const float4* __restrict__ Ct4,
    const float* __restrict__ xsq, const float* __restrict__ csq,
    int* __restrict__ lab, int N)
{
#pragma clang fp contract(off)
  __shared__ float4 Xs4[16 * 128];           // 16 points x 512 floats = 32KB
  const int t = threadIdx.x;
  const int p0 = blockIdx.x * 16;
  const float4* Xg = (const float4*)(X + (size_t)p0 * HID);
  for (int i = t; i < 16 * 128; i += 256) Xs4[i] = Xg[i];
  __syncthreads();

  const int w = t >> 6, c = t & 63;
  const int pb = w * 4 * 128;
  float s0[4], s1[4];
#pragma unroll
  for (int pt = 0; pt < 4; pt++) { s0[pt] = 0.f; s1[pt] = 0.f; }

#pragma unroll 4
  for (int k4 = 0; k4 < 64; k4++) {          // k 0..255
    float4 ct = Ct4[(size_t)k4 * KCL + c];
#pragma unroll
    for (int pt = 0; pt < 4; pt++) {
      float4 xq = Xs4[pb + pt * 128 + k4];
      float s = s0[pt];
      s = fmaf(xq.x, ct.x, s);
      s = fmaf(xq.y, ct.y, s);
      s = fmaf(xq.z, ct.z, s);
      s = fmaf(xq.w, ct.w, s);
      s0[pt] = s;
    }
  }
#pragma unroll 4
  for (int k4 = 64; k4 < 128; k4++) {        // k 256..511
    float4 ct = Ct4[(size_t)k4 * KCL + c];
#pragma unroll
    for (int pt = 0; pt < 4; pt++) {
      float4 xq = Xs4[pb + pt * 128 + k4];
      float s = s1[pt];
      s = fmaf(xq.x, ct.x, s);
      s = fmaf(xq.y, ct.y, s);
      s = fmaf(xq.z, ct.z, s);
      s = fmaf(xq.w, ct.w, s);
      s1[pt] = s;
    }
  }

#pragma unroll
  for (int pt = 0; pt < 4; pt++) {
    int p = p0 + (w * 4 + pt);
    float dot = s0[pt] + s1[pt];
    float t2 = 2.0f * dot;
    float u = xsq[p] - t2;
    float sc = u + csq[c];
    float bv = sc; int bi = c;
#pragma unroll
    for (int m = 32; m; m >>= 1) {
      float ov = __shfl_xor(bv, m);
      int   oi = __shfl_xor(bi, m);
      if (ov < bv || (ov == bv && oi < bi)) { bv = ov; bi = oi; }
    }
    if (c == 0 && p < N) lab[p] = bi;
  }
}

// ---- order-preserving cluster index lists (chunk-major, wave-major, lane-rank) ----

__global__ __launch_bounds__(256) void k_count(
    const int* __restrict__ lab, int* __restrict__ cntch, int N)
{
  int ch = blockIdx.x;
  int p = ch * CHSZ + threadIdx.x;
  int l = (p < N) ? lab[p] : -1;
  int w = threadIdx.x >> 6, lane = threadIdx.x & 63;
  __shared__ int wc[4][64];
  for (int cc = 0; cc < 64; cc++) {
    unsigned long long mm = __ballot(l == cc);
    if (lane == cc) wc[w][cc] = __popcll(mm);
  }
  __syncthreads();
  if (threadIdx.x < 64) {
    int cc = threadIdx.x;
    cntch[ch * 64 + cc] = wc[0][cc] + wc[1][cc] + wc[2][cc] + wc[3][cc];
  }
}

__global__ __launch_bounds__(64) void k_prefix(
    const int* __restrict__ cntch, int* __restrict__ off,
    int* __restrict__ base, int* __restrict__ cnt, int CH)
{
  int c = threadIdx.x;
  int run = 0;
#pragma unroll 8
  for (int ch = 0; ch < CH; ch++) { off[ch * 64 + c] = run; run += cntch[ch * 64 + c]; }
  cnt[c] = run;
  __shared__ int tot[64];
  tot[c] = run;
  __syncthreads();
  if (c == 0) {
    int b = 0;
    for (int cc = 0; cc < 64; cc++) { base[cc] = b; b += tot[cc]; }
  }
  __syncthreads();
  int b = base[c];
#pragma unroll 8
  for (int ch = 0; ch < CH; ch++) off[ch * 64 + c] += b;
}

__global__ __launch_bounds__(256) void k_scatter(
    const int* __restrict__ lab, const int* __restrict__ off,
    int* __restrict__ list, int N)
{
  int ch = blockIdx.x;
  int p = ch * CHSZ + threadIdx.x;
  int l = (p < N) ? lab[p] : -1;
  int w = threadIdx.x >> 6, lane = threadIdx.x & 63;
  __shared__ int wc[4][64];
  int rank = 0;
  for (int cc = 0; cc < 64; cc++) {
    unsigned long long mm = __ballot(l == cc);
    if (lane == cc) wc[w][cc] = __popcll(mm);
    if (l == cc) rank = __popcll(mm & ((1ull << lane) - 1ull));
  }
  __syncthreads();
  if (p < N) {
    int before = 0;
    for (int ww = 0; ww < 4; ww++) if (ww < w) before += wc[ww][l];
    list[off[ch * 64 + l] + before + rank] = p;
  }
}

// fused: segment sums (sequential ascending p, bit-exact np.add.at) +
// centers update + csq + packed Ct4 transpose. One block per cluster.
__global__ __launch_bounds__(512) void np_seg_update_kernel(
    const float* __restrict__ X, const int* __restrict__ list,
    const int* __restrict__ base, const int* __restrict__ cnt,
    float* __restrict__ cen, float* __restrict__ csq, float* __restrict__ Ct4f)
{
#pragma clang fp contract(off)
  __shared__ float row[512];
  const int c = blockIdx.x;
  const int d = threadIdx.x;
  const int n = cnt[c];
  const int* lp = list + base[c];
  float s = 0.f;
  int i = 0;
  for (; i + 8 <= n; i += 8) {
    int p0 = lp[i + 0], p1 = lp[i + 1], p2 = lp[i + 2], p3 = lp[i + 3];
    int p4 = lp[i + 4], p5 = lp[i + 5], p6 = lp[i + 6], p7 = lp[i + 7];
    float x0 = X[(size_t)p0 * HID + d];
    float x1 = X[(size_t)p1 * HID + d];
    float x2 = X[(size_t)p2 * HID + d];
    float x3 = X[(size_t)p3 * HID + d];
    float x4 = X[(size_t)p4 * HID + d];
    float x5 = X[(size_t)p5 * HID + d];
    float x6 = X[(size_t)p6 * HID + d];
    float x7 = X[(size_t)p7 * HID + d];
    s = s + x0; s = s + x1; s = s + x2; s = s + x3;
    s = s + x4; s = s + x5; s = s + x6; s = s + x7;
  }
  for (; i < n; i++) s = s + X[(size_t)lp[i] * HID + d];

  float v;
  if (n > 0) {
    v = s / fmaxf((float)n, 1.0f);
    cen[(size_t)c * HID + d] = v;
  } else {
    v = cen[(size_t)c * HID + d];
  }
  row[d] = v;
  __syncthreads();
  if (d < 64) {
    float sq = np_pw512_sq(row, d);
    if (d == 0) csq[c] = sq;
  }
  Ct4f[((size_t)(d >> 2) * KCL + c) * 4 + (d & 3)] = v;
}

__global__ void copy_f32_kernel(const float* __restrict__ s, float* __restrict__ d, int n)
{
  int i = blockIdx.x * blockDim.x + threadIdx.x;
  if (i < n) d[i] = s[i];
}
__global__ void lab_to_f32_kernel(const int* __restrict__ s, float* __restrict__ d, int n)
{
  int i = blockIdx.x * blockDim.x + threadIdx.x;
  if (i < n) d[i] = (float)s[i];
}

// ======================================================================
// fast f32 path for out1 / u1 / u2 (lenient threshold)
// ======================================================================

__global__ __launch_bounds__(256) void rownorm_kernel(float* __restrict__ M, int N)
{
  int r = blockIdx.x * 4 + (threadIdx.x >> 6);
  int lane = threadIdx.x & 63;
  if (r >= N) return;
  float* row = M + (size_t)r * HID;
  float4 v0 = *reinterpret_cast<const float4*>(&row[lane * 8]);
  float4 v1 = *reinterpret_cast<const float4*>(&row[lane * 8 + 4]);
  float s = v0.x*v0.x + v0.y*v0.y + v0.z*v0.z + v0.w*v0.w
          + v1.x*v1.x + v1.y*v1.y + v1.z*v1.z + v1.w*v1.w;
#pragma unroll
  for (int off = 32; off; off >>= 1) s += __shfl_xor(s, off);
  float nrm = fmaxf(sqrtf(s), 1e-12f);
  v0.x /= nrm; v0.y /= nrm; v0.z /= nrm; v0.w /= nrm;
  v1.x /= nrm; v1.y /= nrm; v1.z /= nrm; v1.w /= nrm;
  *reinterpret_cast<float4*>(&row[lane * 8]) = v0;
  *reinterpret_cast<float4*>(&row[lane * 8 + 4]) = v1;
}

__global__ __launch_bounds__(256) void clf_softmax_kernel(
    const float* __restrict__ X, const float* __restrict__ W,
    const float* __restrict__ bias, float* __restrict__ U, int N)
{
  int p = blockIdx.x * 4 + (threadIdx.x >> 6);
  int c = threadIdx.x & 63;
  if (p >= N) return;
  const float* xr = X + (size_t)p * HID;
  float acc = 0.f;
  for (int d = 0; d < HID; d++) acc = fmaf(xr[d], W[(size_t)d * KCL + c], acc);
  float l = acc + bias[c];
  float mx = l;
#pragma unroll
  for (int m = 32; m; m >>= 1) mx = fmaxf(mx, __shfl_xor(mx, m));
  float e = expf(l - mx);
  float s = e;
#pragma unroll
  for (int m = 32; m; m >>= 1) s += __shfl_xor(s, m);
  U[(size_t)p * KCL + c] = e / s;
}

extern "C" void kernel_launch(void* const* d_in, const int* in_sizes, int n_in,
                              void* d_out, int out_size, void* d_ws, size_t ws_size,
                              hipStream_t stream)
{
  const float* x  = (const float*)d_in[0];
  const float* xw = (const float*)d_in[1];
  const float* W1 = (const float*)d_in[2];
  const float* b1 = (const float*)d_in[3];
  const float* W2 = (const float*)d_in[4];
  const float* b2 = (const float*)d_in[5];
  const float* Wc = (const float*)d_in[6];
  const float* bc = (const float*)d_in[7];

  const int N = in_sizes[0] / ND;          // 50000
  float* out  = (float*)d_out;
  float* out1 = out;
  float* out2 = out1 + (size_t)N * HID;
  float* labf = out2 + (size_t)N * HID;
  float* cenf = labf + N;
  float* u1   = cenf + (size_t)KCL * HID;
  float* u2   = u1 + (size_t)N * KCL;

  const int CH = (N + CHSZ - 1) / CHSZ;    // 196

  // scratch in u2 region (overwritten by the final u2 softmax, which runs last)
  float* cen   = u2;                        // 64*512
  float* Ct4f  = cen + KCL * HID;           // 128*64*4 floats (16B-aligned)
  float* csq   = Ct4f + 128 * KCL * 4;      // 64
  float* xsq   = csq + KCL;                 // N
  int*   cnt   = (int*)(xsq + N);           // 64
  int*   lab   = cnt + KCL;                 // N
  int*   list  = lab + N;                   // N
  int*   cntch = list + N;                  // CH*64
  int*   off   = cntch + CH * 64;           // CH*64
  int*   base  = off + CH * 64;             // 64
  const float4* Ct4 = (const float4*)Ct4f;

  const int pblocks = (N + 3) / 4;
  const int gblocks = N / 8;                // 6250
  const int lblocks = (N + 15) / 16;        // 3125

  // ---- np-bitwise kmeans pipeline ----
  np_gemm2_kernel<<<gblocks, 512, 0, stream>>>(xw, W2, b2, out2);
  np_rownorm_xsq_kernel<<<pblocks, 256, 0, stream>>>(out2, xsq, N);
  copy_f32_kernel<<<(KCL * HID + 255) / 256, 256, 0, stream>>>(out2, cen, KCL * HID);
  np_csqT_kernel<<<KCL, 64, 0, stream>>>(cen, csq, Ct4f);

  for (int it = 0; it < KM_ITERS; ++it) {
    np_label_kernel<<<lblocks, 256, 0, stream>>>(out2, Ct4, xsq, csq, lab, N);
    k_count<<<CH, 256, 0, stream>>>(lab, cntch, N);
    k_prefix<<<1, 64, 0, stream>>>(cntch, off, base, cnt, CH);
    k_scatter<<<CH, 256, 0, stream>>>(lab, off, list, N);
    np_seg_update_kernel<<<KCL, 512, 0, stream>>>(out2, list, base, cnt, cen, csq, Ct4f);
  }
  np_label_kernel<<<lblocks, 256, 0, stream>>>(out2, Ct4, xsq, csq, lab, N);

  lab_to_f32_kernel<<<(N + 255) / 256, 256, 0, stream>>>(lab, labf, N);
  copy_f32_kernel<<<(KCL * HID + 255) / 256, 256, 0, stream>>>(cen, cenf, KCL * HID);

  // ---- fast outputs (auto-pass numerics) ----
  np_gemm2_kernel<<<gblocks, 512, 0, stream>>>(x, W1, b1, out1);
  rownorm_kernel<<<pblocks, 256, 0, stream>>>(out1, N);
  clf_softmax_kernel<<<pblocks, 256, 0, stream>>>(out1, Wc, bc, u1, N);
  clf_softmax_kernel<<<pblocks, 256, 0, stream>>>(out2, Wc, bc, u2, N);  // last: clobbers scratch
}